// Round 4
// baseline (484.167 us; speedup 1.0000x reference)
//
#include <hip/hip_runtime.h>

#define N_NODES 50000
#define N_EDGES 1600000
#define F_IN 256
#define F_OUT 64
#define ALPHA 0.2f

#define SCAN_BLOCKS 250
#define SCAN_CHUNK  200   // 250*200 = 50000 exact

// ---------------------------------------------------------------------------
// Kernel A: Wh = x @ W with W staged in LDS (64KB). 512-thread blocks so the
// 2-blocks/CU LDS limit still gives 16 waves/CU (vs 8 with 256-thr blocks).
// 8 nodes per wave, lane = out feature. Grid sized so each wave does one
// 8-node group. Epilogue: wave reductions for s_src / s_dst.
// ---------------------------------------------------------------------------
__global__ __launch_bounds__(512) void gat_gemm(
    const float* __restrict__ x, const float* __restrict__ W,
    const float* __restrict__ a, float* __restrict__ Wh,
    float* __restrict__ s_src, float* __restrict__ s_dst)
{
    __shared__ float Wl[F_IN * F_OUT];  // 64 KB
    const int t = threadIdx.x;
    {
        const float4* __restrict__ Wv = (const float4*)W;
        float4* Wlv = (float4*)Wl;
        #pragma unroll
        for (int i = 0; i < (F_IN * F_OUT / 4) / 512; ++i)   // 8 iters
            Wlv[t + i * 512] = Wv[t + i * 512];
    }
    __syncthreads();

    const int lane = t & 63;
    const int wave = blockIdx.x * 8 + (t >> 6);
    const int nw   = gridDim.x * 8;
    const float a0 = a[lane];
    const float a1 = a[F_OUT + lane];

    const int NPW = 8;
    for (int g = wave; g < N_NODES / NPW; g += nw) {
        const int node = g * NPW;
        const float4* __restrict__ xr = (const float4*)(x + (size_t)node * F_IN);
        float acc[NPW];
        #pragma unroll
        for (int j = 0; j < NPW; ++j) acc[j] = 0.f;

        #pragma unroll 2
        for (int k4 = 0; k4 < F_IN / 4; ++k4) {
            float4 xv[NPW];
            #pragma unroll
            for (int j = 0; j < NPW; ++j) xv[j] = xr[j * (F_IN / 4) + k4];
            const float w0 = Wl[(4 * k4 + 0) * F_OUT + lane];
            const float w1 = Wl[(4 * k4 + 1) * F_OUT + lane];
            const float w2 = Wl[(4 * k4 + 2) * F_OUT + lane];
            const float w3 = Wl[(4 * k4 + 3) * F_OUT + lane];
            #pragma unroll
            for (int j = 0; j < NPW; ++j)
                acc[j] = fmaf(xv[j].x, w0, fmaf(xv[j].y, w1,
                         fmaf(xv[j].z, w2, fmaf(xv[j].w, w3, acc[j]))));
        }
        #pragma unroll
        for (int j = 0; j < NPW; ++j) {
            Wh[(size_t)(node + j) * F_OUT + lane] = acc[j];
            float p = acc[j] * a0;
            float q = acc[j] * a1;
            #pragma unroll
            for (int off = 32; off > 0; off >>= 1) {
                p += __shfl_down(p, off);
                q += __shfl_down(q, off);
            }
            if (lane == 0) { s_src[node + j] = p; s_dst[node + j] = q; }
        }
    }
}

// ---------------------------------------------------------------------------
// Kernel B1: degree histogram of src
// ---------------------------------------------------------------------------
__global__ __launch_bounds__(256) void gat_hist(
    const int* __restrict__ edge, int* __restrict__ deg)
{
    const int e = blockIdx.x * blockDim.x + threadIdx.x;
    if (e < N_EDGES) atomicAdd(&deg[edge[e]], 1);
}

// ---------------------------------------------------------------------------
// Kernels B2a/b/c: hierarchical exclusive scan of deg -> row_start, cursor
// ---------------------------------------------------------------------------
__global__ __launch_bounds__(256) void scan_part(
    const int* __restrict__ deg, int* __restrict__ part)
{
    __shared__ int sm[256];
    const int t = threadIdx.x;
    const int base = blockIdx.x * SCAN_CHUNK;
    sm[t] = (t < SCAN_CHUNK) ? deg[base + t] : 0;
    __syncthreads();
    #pragma unroll
    for (int off = 128; off > 0; off >>= 1) {
        if (t < off) sm[t] += sm[t + off];
        __syncthreads();
    }
    if (t == 0) part[blockIdx.x] = sm[0];
}

__global__ __launch_bounds__(256) void scan_mid(
    const int* __restrict__ part, int* __restrict__ partscan,
    int* __restrict__ row_start)
{
    __shared__ int sm[256];
    const int t = threadIdx.x;
    const int v = (t < SCAN_BLOCKS) ? part[t] : 0;
    sm[t] = v;
    __syncthreads();
    #pragma unroll
    for (int off = 1; off < 256; off <<= 1) {
        const int u = (t >= off) ? sm[t - off] : 0;
        __syncthreads();
        sm[t] += u;
        __syncthreads();
    }
    if (t < SCAN_BLOCKS) partscan[t] = sm[t] - v;          // exclusive
    if (t == SCAN_BLOCKS - 1) row_start[N_NODES] = sm[t];  // total = N_EDGES
}

__global__ __launch_bounds__(256) void scan_final(
    const int* __restrict__ deg, const int* __restrict__ partscan,
    int* __restrict__ row_start, int* __restrict__ cursor)
{
    __shared__ int sm[256];
    const int t = threadIdx.x;
    const int base = blockIdx.x * SCAN_CHUNK;
    const int v = (t < SCAN_CHUNK) ? deg[base + t] : 0;
    sm[t] = v;
    __syncthreads();
    #pragma unroll
    for (int off = 1; off < 256; off <<= 1) {
        const int u = (t >= off) ? sm[t - off] : 0;
        __syncthreads();
        sm[t] += u;
        __syncthreads();
    }
    if (t < SCAN_CHUNK) {
        const int excl = sm[t] - v + partscan[blockIdx.x];
        row_start[base + t] = excl;
        cursor[base + t] = excl;
    }
}

// ---------------------------------------------------------------------------
// Kernel B3: scatter dst into CSR order (4B entries — ee is recomputed in
// the aggregate from the L2-resident s_src/s_dst tables, halving scattered
// write traffic here).
// ---------------------------------------------------------------------------
__global__ __launch_bounds__(256) void gat_scatter(
    const int* __restrict__ edge, int* __restrict__ cursor,
    int* __restrict__ csr)
{
    const int e = blockIdx.x * blockDim.x + threadIdx.x;
    if (e < N_EDGES) {
        const int s = edge[e];
        const int pos = atomicAdd(&cursor[s], 1);
        csr[pos] = edge[N_EDGES + e];
    }
}

// ---------------------------------------------------------------------------
// Kernel C: aggregation, wave per node. Batch of 64 edges: coalesced csr
// read, per-lane ee recompute, then half-wave-per-edge broadcast loop —
// lanes 0-31 process even edges, 32-63 odd edges, each lane covering two
// features via float2 gathers. Rowsum via per-lane partials + one wave
// reduction. Finalize (divide + ELU) fused. No atomics.
// ---------------------------------------------------------------------------
__global__ __launch_bounds__(256) void gat_aggregate(
    const int* __restrict__ row_start, const int* __restrict__ csr,
    const float* __restrict__ s_src, const float* __restrict__ s_dst,
    const float* __restrict__ Wh, float* __restrict__ out)
{
    const int lane = threadIdx.x & 63;
    const int half = lane >> 5;        // 0: even edges, 1: odd edges
    const int hl   = lane & 31;        // feature pair index
    const int wave = (int)((blockIdx.x * blockDim.x + threadIdx.x) >> 6);
    const int nw   = (int)((gridDim.x * blockDim.x) >> 6);
    const float2* __restrict__ Wh2 = (const float2*)Wh;

    for (int i = wave; i < N_NODES; i += nw) {
        const int r0 = row_start[i];
        const int r1 = row_start[i + 1];
        const float si = s_src[i];                 // wave-uniform
        float2 acc = make_float2(0.f, 0.f);
        float rsum_part = 0.f;

        for (int b = r0; b < r1; b += 64) {
            int m = r1 - b;
            if (m > 64) m = 64;
            int c = 0;
            float ee = 0.f;
            if (lane < m) {
                c = csr[b + lane];                 // coalesced 4B
                const float score = si + s_dst[c]; // 4B gather, L1/L2-resident
                const float lr = score > 0.f ? score : ALPHA * score;
                ee = __expf(-lr);
            }
            rsum_part += ee;
            for (int t = 0; t < m; t += 2) {
                const int e = t + half;            // ee==0 for e>=m pad
                const int   dt = __shfl(c, e);
                const float et = __shfl(ee, e);
                const float2 wv = Wh2[(size_t)dt * (F_OUT / 2) + hl]; // 256B/edge
                acc.x = fmaf(et, wv.x, acc.x);
                acc.y = fmaf(et, wv.y, acc.y);
            }
        }
        // combine the two half-wave accumulators (lane ^ 32 holds the
        // other parity's contribution to the same feature pair)
        acc.x += __shfl_xor(acc.x, 32);
        acc.y += __shfl_xor(acc.y, 32);
        // full wave reduction for rowsum
        #pragma unroll
        for (int off = 32; off > 0; off >>= 1)
            rsum_part += __shfl_xor(rsum_part, off);

        float2 v = make_float2(acc.x / rsum_part, acc.y / rsum_part);
        v.x = v.x > 0.f ? v.x : (__expf(v.x) - 1.f);
        v.y = v.y > 0.f ? v.y : (__expf(v.y) - 1.f);
        if (half == 0)
            ((float2*)out)[(size_t)i * (F_OUT / 2) + hl] = v;  // 256B store
    }
}

extern "C" void kernel_launch(void* const* d_in, const int* in_sizes, int n_in,
                              void* d_out, int out_size, void* d_ws, size_t ws_size,
                              hipStream_t stream) {
    const float* x    = (const float*)d_in[0];
    const int*   edge = (const int*)  d_in[1];
    const float* W    = (const float*)d_in[2];
    const float* a    = (const float*)d_in[3];
    float* out = (float*)d_out;

    float* ws        = (float*)d_ws;
    float* Wh        = ws;                                    // 3,200,000 f
    int*   csr       = (int*)(Wh + (size_t)N_NODES * F_OUT);  // 1,600,000 i
    float* s_src     = (float*)(csr + N_EDGES);               // 50,000 f
    float* s_dst     = s_src + N_NODES;                       // 50,000 f
    int*   deg       = (int*)(s_dst + N_NODES);               // 50,000 i
    int*   part      = deg + N_NODES;                         // 256 i
    int*   partscan  = part + 256;                            // 256 i
    int*   row_start = partscan + 256;                        // 50,001 i
    int*   cursor    = row_start + N_NODES + 1;               // 50,000 i

    hipMemsetAsync(deg, 0, (size_t)N_NODES * sizeof(int), stream);

    gat_gemm<<<782, 512, 0, stream>>>(x, W, a, Wh, s_src, s_dst);
    gat_hist<<<N_EDGES / 256, 256, 0, stream>>>(edge, deg);
    scan_part<<<SCAN_BLOCKS, 256, 0, stream>>>(deg, part);
    scan_mid<<<1, 256, 0, stream>>>(part, partscan, row_start);
    scan_final<<<SCAN_BLOCKS, 256, 0, stream>>>(deg, partscan, row_start, cursor);
    gat_scatter<<<N_EDGES / 256, 256, 0, stream>>>(edge, cursor, csr);
    gat_aggregate<<<3125, 256, 0, stream>>>(row_start, csr, s_src, s_dst, Wh, out);
}